// Round 9
// baseline (62.176 us; speedup 1.0000x reference)
//
#include <hip/hip_runtime.h>
#include <hip/hip_bf16.h>

typedef __attribute__((ext_vector_type(8))) short short8;
typedef __attribute__((ext_vector_type(4))) float f32x4;
typedef unsigned short u16;
typedef unsigned int u32;

#define NROWS 8192
#define HALF  4096
#define DIM   256
#define TEMP_INV 2.0f   // 1/temperature
#define NBT 32                        // 8192/256 tiles per side
#define NBLK (NBT * (NBT + 1) / 2)    // 528 triangular tiles
#define NSLAB 128                     // 32 k-slots * 4 sub-slots

#define BARRIER() asm volatile("s_barrier" ::: "memory")
#define WAITV(n)  asm volatile("s_waitcnt vmcnt(" #n ")" ::: "memory")

__device__ __forceinline__ u16 f2bf(float f) {
    union { float f; u32 i; } c; c.f = f;
    u32 lsb = (c.i >> 16) & 1;
    c.i += 0x7fffu + lsb;   // round-to-nearest-even
    return (u16)(c.i >> 16);
}

// ---------------- kernel 0: zero the slab ------------------------------------
__global__ __launch_bounds__(256) void zero_k(float4* __restrict__ p) {
    p[blockIdx.x * 256 + threadIdx.x] = float4{0.f, 0.f, 0.f, 0.f};
}

// ---------------- kernel 1: normalize rows, write bf16 ----------------------
__global__ __launch_bounds__(256) void normalize_k(const float* __restrict__ zi,
                                                   const float* __restrict__ zj,
                                                   u16* __restrict__ zn) {
    const int row  = blockIdx.x * 4 + (threadIdx.x >> 6);
    const int lane = threadIdx.x & 63;
    const float* src = (row < HALF) ? (zi + (size_t)row * DIM)
                                    : (zj + (size_t)(row - HALF) * DIM);
    float4 v = reinterpret_cast<const float4*>(src)[lane];
    float ss = v.x * v.x + v.y * v.y + v.z * v.z + v.w * v.w;
    #pragma unroll
    for (int m = 32; m; m >>= 1) ss += __shfl_xor(ss, m);
    const float inv = 1.0f / fmaxf(sqrtf(ss), 1e-8f);
    ushort4 o;
    o.x = f2bf(v.x * inv); o.y = f2bf(v.y * inv);
    o.z = f2bf(v.z * inv); o.w = f2bf(v.w * inv);
    reinterpret_cast<ushort4*>(zn + (size_t)row * DIM)[lane] = o;
}

// ---------------- kernel 2: 256^2 fine-phase triangular GEMM ----------------
// 8 waves (2M x 4N), per-wave 128x64 out. K=256 = 4 K-tiles of BK=64, 2 LDS
// dbufs (128 KiB). Per K-tile 4 quadrant-phases, each {ds_read subtile ||
// stage 1 quarter -> barrier -> 16 MFMA -> barrier}; counted vmcnt (never 0
// mid-loop). Quarter staged into dbuf d only after the barrier certifying
// all reads of d's previous tile completed.
__device__ __forceinline__ void gload16(const void* g, void* lds) {
    __builtin_amdgcn_global_load_lds(
        (const __attribute__((address_space(1))) u32*)g,
        (__attribute__((address_space(3))) u32*)lds, 16, 0, 0);
}

__global__ __launch_bounds__(512, 2) void gemm_exp_rowsum(const u16* __restrict__ zn,
                                                          float* __restrict__ slab,
                                                          float* __restrict__ pos) {
    // XCD-aware bijective swizzle (528 = 8 * 66)
    const int b0 = blockIdx.x;
    const int b  = (b0 & 7) * (NBLK / 8) + (b0 >> 3);
    // Triangular decode: b -> (by, bx), by <= bx < 32
    int by = (int)((65.0f - sqrtf(65.0f * 65.0f - 8.0f * (float)b)) * 0.5f);
    while (by * (65 - by) / 2 > b) --by;
    while ((by + 1) * (64 - by) / 2 <= b) ++by;
    const int bx = by + (b - by * (65 - by) / 2);
    const bool diag  = (by == bx);
    const bool isPos = (bx - by == 16);

    const int rowBase = by * 256;
    const int colBase = bx * 256;

    __shared__ u16 AL[2 * 16384];   // 2 dbufs x 256x64 bf16 = 64 KiB
    __shared__ u16 BL[2 * 16384];   // 64 KiB  -> total 128 KiB

    const int tid  = threadIdx.x;
    const int w    = tid >> 6;      // 0..7
    const int lane = tid & 63;
    const int wm = w >> 2;          // 0..1 -> 128-row strip
    const int wn = w & 3;           // 0..3 -> 64-col strip

    f32x4 acc[8][4] = {};

    // ---- staging: LDS linear, source chunk pre-swizzled, key = row&7
    // (rows are 128B = 8 x 16B chunks). q: 0=A.h0 1=A.h1 2=B.h0 3=B.h1
    auto stageQ = [&](int d, int kt, int q) {
        const int base = (q < 2) ? rowBase : colBase;
        const int h = q & 1;
        const u16* g = zn + (size_t)(base + h * 128 + (tid >> 3)) * DIM
                       + kt * 64 + (((tid & 7) ^ ((tid >> 3) & 7)) * 8);
        u16* l = ((q < 2) ? AL : BL) + d * 16384 + h * 8192 + tid * 8;
        gload16(g, l);                       // rows 0..63 of the half
        gload16(g + (size_t)64 * DIM, l + 4096);   // rows 64..127
    };

    // ---- ds_read bases: chunk(ks) = (ks*4 + (lane>>4)) ^ (lane&7)
    const int laneR = lane & 15;
    const int ch0 = ((lane >> 4) ^ (lane & 7)) * 16;
    const int ch1 = ((4 + (lane >> 4)) ^ (lane & 7)) * 16;
    const char* ALc = (const char*)AL;
    const char* BLc = (const char*)BL;
    const u32 Ab = (u32)((wm * 128 + laneR) * 128);
    const u32 Bb = (u32)((wn * 64 + laneR) * 128);

    short8 af[4][2];    // A-frags for current mi-half (qa)
    short8 bfr[4][2];   // B-frags, all 4 ni live across the tile

    auto rdA = [&](int d, int qa) {
        #pragma unroll
        for (int m = 0; m < 4; ++m) {
            const u32 o = d * 32768 + qa * 8192 + m * 2048 + Ab;
            af[m][0] = *reinterpret_cast<const short8*>(ALc + o + ch0);
            af[m][1] = *reinterpret_cast<const short8*>(ALc + o + ch1);
        }
    };
    auto rdB = [&](int d, int qb) {
        #pragma unroll
        for (int n = 0; n < 2; ++n) {
            const int ni = qb * 2 + n;
            const u32 o = d * 32768 + ni * 2048 + Bb;
            bfr[ni][0] = *reinterpret_cast<const short8*>(BLc + o + ch0);
            bfr[ni][1] = *reinterpret_cast<const short8*>(BLc + o + ch1);
        }
    };
    auto MFMAQ = [&](int qa, int qb) {
        __builtin_amdgcn_s_setprio(1);
        #pragma unroll
        for (int m = 0; m < 4; ++m)
            #pragma unroll
            for (int n = 0; n < 2; ++n) {
                const int ni = qb * 2 + n;
                acc[qa * 4 + m][ni] = __builtin_amdgcn_mfma_f32_16x16x32_bf16(
                    af[m][0], bfr[ni][0], acc[qa * 4 + m][ni], 0, 0, 0);
                acc[qa * 4 + m][ni] = __builtin_amdgcn_mfma_f32_16x16x32_bf16(
                    af[m][1], bfr[ni][1], acc[qa * 4 + m][ni], 0, 0, 0);
            }
        __builtin_amdgcn_s_setprio(0);
    };

    // prologue: tiles 0,1 fully staged (16 loads/thread)
    #pragma unroll
    for (int q = 0; q < 4; ++q) stageQ(0, 0, q);
    #pragma unroll
    for (int q = 0; q < 4; ++q) stageQ(1, 1, q);
    WAITV(8);   // tile0's 8 landed; tile1's 8 may fly
    BARRIER();

    #pragma unroll
    for (int t = 0; t < 4; ++t) {
        const int d = t & 1;
        const bool mid = (t == 1 || t == 2);   // stage quarters 1-3 of t+1
        // q0: A-lo + B-lo reads || stage
        rdA(d, 0); rdB(d, 0);
        if (mid) stageQ(d ^ 1, t + 1, 1);
        BARRIER();
        MFMAQ(0, 0);
        BARRIER();
        // q1: B-hi reads || stage
        rdB(d, 1);
        if (mid) stageQ(d ^ 1, t + 1, 2);
        BARRIER();
        MFMAQ(0, 1);
        BARRIER();
        // q2: A-hi reads || stage  (closing barrier certifies dbuf d free)
        rdA(d, 1);
        if (mid) stageQ(d ^ 1, t + 1, 3);
        BARRIER();
        MFMAQ(1, 0);
        BARRIER();
        // q3: no reads; first quarter of t+2 goes into dbuf d (now free)
        if (t <= 1) stageQ(d, t + 2, 0);
        MFMAQ(1, 1);
        if (t == 0 || t == 1) { WAITV(2); }   // next tile landed; newest 2 fly
        else if (t == 2)      { WAITV(0); }   // final tile landed
        if (t < 3) BARRIER();
    }

    // -------- epilogue: exp + row/col partial sums, unique slab slots --------
    // C/D layout: col = lane&15, row = (lane>>4)*4 + v
    float cs[4] = {0.f, 0.f, 0.f, 0.f};
    float* rowSlot = slab + (size_t)(bx * 4 + wn) * NROWS + rowBase + wm * 128;
    #pragma unroll
    for (int mi = 0; mi < 8; ++mi) {
        f32x4 rs = {0.f, 0.f, 0.f, 0.f};
        #pragma unroll
        for (int ni = 0; ni < 4; ++ni)
            #pragma unroll
            for (int v = 0; v < 4; ++v) {
                const int R = wm * 128 + mi * 16 + (lane >> 4) * 4 + v;
                const int C = wn * 64 + ni * 16 + (lane & 15);
                float e = __expf(TEMP_INV * acc[mi][ni][v]);
                if (diag && R == C) e = 0.f;   // exclude self-similarity
                rs[v] += e;
                cs[ni] += e;
            }
        #pragma unroll
        for (int v = 0; v < 4; ++v) {
            float s = rs[v];
            s += __shfl_xor(s, 1);
            s += __shfl_xor(s, 2);
            s += __shfl_xor(s, 4);
            s += __shfl_xor(s, 8);
            rs[v] = s;
        }
        if ((lane & 15) == 0)   // 4 lanes -> one coalesced 64B store
            *reinterpret_cast<f32x4*>(rowSlot + mi * 16 + (lane >> 4) * 4) = rs;
    }
    if (!diag) {
        // symmetric col sums; slot (by*4 + (wn&1)*2 + wm) is collision-free
        float* colSlot = slab + (size_t)(by * 4 + (wn & 1) * 2 + wm) * NROWS
                         + colBase + wn * 64;
        #pragma unroll
        for (int ni = 0; ni < 4; ++ni) {
            float c = cs[ni];
            c += __shfl_xor(c, 16);
            c += __shfl_xor(c, 32);
            if (lane < 16)
                colSlot[ni * 16 + lane] = c;
        }
    }
    if (isPos) {
        // tile-diagonal elements are sim(i, i+HALF)
        #pragma unroll
        for (int mi = 0; mi < 8; ++mi)
            #pragma unroll
            for (int ni = 0; ni < 4; ++ni)
                #pragma unroll
                for (int v = 0; v < 4; ++v) {
                    const int R = wm * 128 + mi * 16 + (lane >> 4) * 4 + v;
                    const int C = wn * 64 + ni * 16 + (lane & 15);
                    if (R == C) {
                        const float val = acc[mi][ni][v];
                        pos[rowBase + R] = val;
                        pos[rowBase + R + HALF] = val;
                    }
                }
    }
}

// ---------------- kernel 3: reduce slab rows -> per-block partials ----------
__global__ __launch_bounds__(256) void finalize_k(const float* __restrict__ slab,
                                                  const float* __restrict__ pos,
                                                  float* __restrict__ part) {
    const int row = blockIdx.x * 256 + threadIdx.x;
    float d = 0.f;
    #pragma unroll 8
    for (int j = 0; j < NSLAB; ++j)
        d += slab[(size_t)j * NROWS + row];    // coalesced across threads
    float s = logf(d) - TEMP_INV * pos[row];
    __shared__ float red[256];
    red[threadIdx.x] = s;
    __syncthreads();
    #pragma unroll
    for (int m = 128; m; m >>= 1) {
        if (threadIdx.x < m) red[threadIdx.x] += red[threadIdx.x + m];
        __syncthreads();
    }
    if (threadIdx.x == 0) part[blockIdx.x] = red[0];
}

// ---------------- kernel 4: sum 32 partials (deterministic, no atomics) -----
__global__ __launch_bounds__(64) void sum_k(const float* __restrict__ part,
                                            float* __restrict__ out) {
    float v = (threadIdx.x < 32) ? part[threadIdx.x] : 0.f;
    #pragma unroll
    for (int m = 32; m; m >>= 1) v += __shfl_xor(v, m);
    if (threadIdx.x == 0) out[0] = v * (1.0f / NROWS);
}

extern "C" void kernel_launch(void* const* d_in, const int* in_sizes, int n_in,
                              void* d_out, int out_size, void* d_ws, size_t ws_size,
                              hipStream_t stream) {
    const float* zi = (const float*)d_in[0];
    const float* zj = (const float*)d_in[1];
    float* out = (float*)d_out;

    // workspace: zn bf16 [8192][256] (4 MiB) | slab f32 [128][8192] (4 MiB)
    //            | pos f32 [8192] | part f32 [32]
    u16*   zn   = (u16*)d_ws;
    float* slab = (float*)((char*)d_ws + (size_t)NROWS * DIM * sizeof(u16));
    float* pos  = slab + (size_t)NSLAB * NROWS;
    float* part = pos + NROWS;

    zero_k<<<(NSLAB * NROWS) / (256 * 4), 256, 0, stream>>>((float4*)slab);
    normalize_k<<<NROWS / 4, 256, 0, stream>>>(zi, zj, zn);
    gemm_exp_rowsum<<<NBLK, 512, 0, stream>>>(zn, slab, pos);
    finalize_k<<<NROWS / 256, 256, 0, stream>>>(slab, pos, part);
    sum_k<<<1, 64, 0, stream>>>(part, out);
}